// Round 19
// baseline (338.122 us; speedup 1.0000x reference)
//
#include <hip/hip_runtime.h>
#include <hip/hip_bf16.h>

using bf16 = __hip_bfloat16;
typedef __bf16 bf16x8 __attribute__((ext_vector_type(8)));
typedef float f32x4 __attribute__((ext_vector_type(4)));

constexpr int kDim = 192;
constexpr int kH = 6;
constexpr int kHd = 32;
constexpr int kN = 64;
constexpr int kT = 64;
constexpr int kV = 25;
constexpr int kP = kT * kV;            // 1600 positions per n
constexpr int kNCstride = kDim * kP;   // 307200, per-n stride of (c,t,v)
constexpr float kScale = 0.17677669529663687f;  // 32^-0.5
constexpr float kCoeff = 0.4f;

// ---- setup: h_adj, weights->bf16 (g folded), G/Bb, rpe/proj pack, VT pad ---
__global__ void __launch_bounds__(256) setup_kernel(
    const int* __restrict__ jl, const float* __restrict__ hew,
    const float* __restrict__ hgc, const float* __restrict__ qw,
    const float* __restrict__ kvw, const float* __restrict__ rpe,
    const float* __restrict__ proj_w, const float* __restrict__ lng,
    const float* __restrict__ lnb, int n_hop, float* __restrict__ hadj,
    bf16* __restrict__ Wb, float* __restrict__ G, float* __restrict__ Bb,
    bf16* __restrict__ RPEb, bf16* __restrict__ pwb, bf16* __restrict__ VT) {
  const int bid = blockIdx.x;
  const int tid = threadIdx.x;
  if (bid < 576) {  // Wb[768][192]: rows 0..191 hgc raw; 192..767 [q;kv]*g
    int i = bid * 256 + tid;
    float v;
    if (i < 36864) {
      v = hgc[i];
    } else {
      int local = i - 36864;
      int c = local % kDim;
      v = (local < 36864) ? qw[local] : kvw[local - 36864];
      v *= lng[c];
    }
    Wb[i] = __float2bfloat16(v);
  } else if (bid == 576) {  // h_adj from labels
    __shared__ int lbl[kV];
    __shared__ int cnt[8];
    if (tid < 8) cnt[tid] = 0;
    __syncthreads();
    if (tid < kV) { lbl[tid] = jl[tid]; atomicAdd(&cnt[lbl[tid]], 1); }
    __syncthreads();
    for (int idx = tid; idx < kV * kV; idx += 256) {
      int v = idx / kV, w = idx - v * kV;
      float val = 0.f;
      if (lbl[v] == lbl[w]) val = hew[lbl[v]] / (float)cnt[lbl[v]];
      hadj[idx] = val;
    }
  } else if (bid == 577) {  // pack rpe (zero-padded to 16 hops) + proj_w
    for (int i = tid; i < kH * 16 * kHd; i += 256) {
      int h = i >> 9, hp = (i >> 5) & 15, d = i & 31;
      float v = (hp < n_hop) ? rpe[hp * kDim + h * kHd + d] : 0.f;
      RPEb[i] = __float2bfloat16(v);
    }
    for (int i = tid; i < kDim * kHd; i += 256)
      pwb[i] = __float2bfloat16(proj_w[i]);
  } else if (bid < 722) {  // G[o] = sum W[o][c]*g[c]; Bb[o] = sum W[o][c]*b[c]
    int o = (bid - 578) * 4 + (tid >> 6);
    int lane = tid & 63;
    const float* Wr =
        (o < kDim) ? (qw + (size_t)o * kDim) : (kvw + (size_t)(o - kDim) * kDim);
    float gs = 0.f, bs = 0.f;
    for (int c = lane; c < kDim; c += 64) {
      float wv = Wr[c];
      gs += wv * lng[c];
      bs += wv * lnb[c];
    }
    for (int off = 32; off > 0; off >>= 1) {
      gs += __shfl_down(gs, off);
      bs += __shfl_down(bs, off);
    }
    if (lane == 0) { G[o] = gs; Bb[o] = bs; }
  } else {  // zero VT pad cols 24..31 (one 16B store per row)
    int row = (bid - 722) * 256 + tid;
    if (row < kN * kT * kDim) {
      uint4 z = {0u, 0u, 0u, 0u};
      *reinterpret_cast<uint4*>(reinterpret_cast<char*>(VT) + (size_t)row * 64 +
                                48) = z;
    }
  }
}

// ------- prep per (n,t): pure transpose f32->bf16 + LN stats, no data LDS ---
__global__ void __launch_bounds__(256) prep_kernel(
    const float* __restrict__ x, bf16* __restrict__ XR, float* __restrict__ mu,
    float* __restrict__ rstd) {
  __shared__ float ps[kV][25], ps2[kV][25];
  const int tid = threadIdx.x;
  const int t = blockIdx.x, n = blockIdx.y;
  const float* xb = x + (size_t)n * kNCstride + t * kV;
  size_t ob = ((size_t)n * kP + t * kV) * kDim;
  for (int idx = tid; idx < 600; idx += 256) {
    int p = idx % 25, c8 = idx / 25;  // p fastest -> coalesced row reads
    float a = 0.f, b = 0.f;
    union { uint4 u; __bf16 h[8]; } pk;
#pragma unroll
    for (int i = 0; i < 8; ++i) {
      float v = xb[(size_t)(c8 * 8 + i) * kP + p];
      a += v;
      b += v * v;
      pk.h[i] = (__bf16)v;
    }
    *reinterpret_cast<uint4*>(XR + ob + (size_t)p * kDim + c8 * 8) = pk.u;
    ps[p][c8] = a;
    ps2[p][c8] = b;
  }
  __syncthreads();
  if (tid < kV) {
    float a = 0.f, b = 0.f;
#pragma unroll
    for (int c8 = 0; c8 < 24; ++c8) { a += ps[tid][c8]; b += ps2[tid][c8]; }
    float m = a * (1.f / kDim);
    float var = b * (1.f / kDim) - m * m;
    int gid = n * kP + t * kV + tid;
    mu[gid] = m;
    rstd[gid] = rsqrtf(var + 1e-5f);
  }
}

// ---- MFMA GEMM: out[n][p][o] = A[o][k]*B[n][p][k]; optional LN-fix epilogue,
//      optional V-third -> VT transposed, optional K += f*E fold (VS only).
//      QK/OP stores coalesced via an LDS [p][o] round-trip (1 wave/block). --
template <int OBN, int MOUT, bool VS, bool LNF>
__global__ void __launch_bounds__(64) mfma_gemm_kernel(
    const bf16* __restrict__ A, const bf16* __restrict__ B,
    bf16* __restrict__ out, bf16* __restrict__ VT,
    const float* __restrict__ muA, const float* __restrict__ rsA,
    const float* __restrict__ G, const float* __restrict__ Bb,
    const bf16* __restrict__ OPe, const float* __restrict__ gatef) {
  __shared__ bf16 st[64][70];  // 8.96 KB, [p_local][o_local], stride 70
  int id = blockIdx.x;
  int per = gridDim.x >> 3;  // grid % 8 == 0
  int wg = (id & 7) * per + (id >> 3);
  int n = wg / (25 * OBN);
  int rem = wg - n * (25 * OBN);
  const int pb = (rem / OBN) * 64;
  const int ob = (rem % OBN) * 64;
  const int l = threadIdx.x;
  B += (size_t)n * kNCstride;
  out += (size_t)n * kP * MOUT;
  f32x4 acc[4][4] = {};
  const int lm = l & 15;
  const int lk = (l >> 4) * 8;
  for (int kb = 0; kb < kDim; kb += 32) {
    bf16x8 af[4], bfv[4];
#pragma unroll
    for (int mf = 0; mf < 4; ++mf)
      af[mf] = *reinterpret_cast<const bf16x8*>(
          A + (size_t)(ob + mf * 16 + lm) * kDim + kb + lk);
#pragma unroll
    for (int nf = 0; nf < 4; ++nf)
      bfv[nf] = *reinterpret_cast<const bf16x8*>(
          B + (size_t)(pb + nf * 16 + lm) * kDim + kb + lk);
#pragma unroll
    for (int mf = 0; mf < 4; ++mf)
#pragma unroll
      for (int nf = 0; nf < 4; ++nf)
        acc[mf][nf] = __builtin_amdgcn_mfma_f32_16x16x32_bf16(
            af[mf], bfv[nf], acc[mf][nf], 0, 0, 0);
  }
  const int r0 = (l >> 4) * 4;
  float rsv[4], muv[4], fga[4];
  const bf16* OPn = VS ? (OPe + (size_t)n * kP * kDim) : nullptr;
  if (LNF) {
#pragma unroll
    for (int nf = 0; nf < 4; ++nf) {
      int p = pb + nf * 16 + lm;
      rsv[nf] = rsA[n * kP + p];
      muv[nf] = muA[n * kP + p];
      if (VS) fga[nf] = gatef[n * kT + p / 25];
    }
  }
  if (!VS || ob < 384) {
    // ---- QK/OP path: LN (opt) + K-fold (opt) -> LDS -> coalesced stores ---
#pragma unroll
    for (int mf = 0; mf < 4; ++mf) {
      const int o0 = ob + mf * 16 + r0;
      float ga[4] = {0.f, 0.f, 0.f, 0.f}, ba[4] = {0.f, 0.f, 0.f, 0.f};
      if (LNF) {
        float4 g4 = *reinterpret_cast<const float4*>(G + o0);
        float4 b4 = *reinterpret_cast<const float4*>(Bb + o0);
        ga[0] = g4.x; ga[1] = g4.y; ga[2] = g4.z; ga[3] = g4.w;
        ba[0] = b4.x; ba[1] = b4.y; ba[2] = b4.z; ba[3] = b4.w;
      }
      const bool kfold = VS && (o0 >= 192);  // K range: fold += f*E
#pragma unroll
      for (int nf = 0; nf < 4; ++nf) {
        const int p = pb + nf * 16 + lm;
        float ev[4] = {0.f, 0.f, 0.f, 0.f};
        if (kfold) {
          union { uint2 u; bf16 b[4]; } eld;
          eld.u = *reinterpret_cast<const uint2*>(OPn + (size_t)p * kDim +
                                                  (o0 - 192));
#pragma unroll
          for (int r = 0; r < 4; ++r) ev[r] = __bfloat162float(eld.b[r]);
        }
#pragma unroll
        for (int r = 0; r < 4; ++r) {
          float vvv = acc[mf][nf][r];
          if (LNF) vvv = rsv[nf] * (vvv - muv[nf] * ga[r]) + ba[r];
          if (kfold) vvv += fga[nf] * ev[r];
          st[nf * 16 + lm][mf * 16 + r0 + r] = __float2bfloat16(vvv);
        }
      }
    }
    __syncthreads();
#pragma unroll
    for (int it = 0; it < 8; ++it) {
      int pl = it * 8 + (l >> 3);
      int oc = (l & 7) * 8;
      uint4 v = *reinterpret_cast<const uint4*>(&st[pl][oc]);
      *reinterpret_cast<uint4*>(out + (size_t)(pb + pl) * MOUT + ob + oc) = v;
    }
  } else {  // V third: write transposed VT[(n*64+t)*192 + d][v]
    int tt[4], vv[4];
#pragma unroll
    for (int nf = 0; nf < 4; ++nf) {
      int p = pb + nf * 16 + lm;
      tt[nf] = p / 25;
      vv[nf] = p - tt[nf] * 25;
    }
#pragma unroll
    for (int mf = 0; mf < 4; ++mf) {
      const int o0 = ob + mf * 16 + r0;
      float ga[4], ba[4];
      float4 g4 = *reinterpret_cast<const float4*>(G + o0);
      float4 b4 = *reinterpret_cast<const float4*>(Bb + o0);
      ga[0] = g4.x; ga[1] = g4.y; ga[2] = g4.z; ga[3] = g4.w;
      ba[0] = b4.x; ba[1] = b4.y; ba[2] = b4.z; ba[3] = b4.w;
#pragma unroll
      for (int nf = 0; nf < 4; ++nf) {
        size_t rowb =
            ((size_t)(n * kT + tt[nf]) * kDim + (o0 - 384)) * 32 + vv[nf];
#pragma unroll
        for (int r = 0; r < 4; ++r) {
          float vvv = rsv[nf] * (acc[mf][nf][r] - muv[nf] * ga[r]) + ba[r];
          VT[rowb + (size_t)r * 32] = __float2bfloat16(vvv);
        }
      }
    }
  }
}

// ------ h_adj apply on OP (in place) + fused sred sum + d-term table -------
__global__ void __launch_bounds__(256) haapply_kernel(
    bf16* __restrict__ OP, const float* __restrict__ hadjg,
    const float* __restrict__ w1, float* __restrict__ s_out,
    float* __restrict__ dtbl) {
  __shared__ ushort tile[kV * kDim];  // 9.6 KB
  __shared__ float ha[640];
  __shared__ float red[4];
  __shared__ float dp[600];  // partials for d-term: [w][c8]
  const int tid = threadIdx.x;
  const int t = blockIdx.x, n = blockIdx.y;
  const int nt = n * kT + t;
  size_t base = ((size_t)nt * kV) * kDim;
  for (int i = tid; i < kV * kV; i += 256) ha[i] = hadjg[i];
  const uint2* src = reinterpret_cast<const uint2*>(OP + base);
  uint2* dst2 = reinterpret_cast<uint2*>(tile);
  for (int i = tid; i < kV * kDim / 4; i += 256) dst2[i] = src[i];
  __syncthreads();
  float ssum = 0.f;
  for (int idx = tid; idx < 600; idx += 256) {
    int c8 = idx % 24, w = idx / 24;  // c8 fastest -> coalesced writes
    float acc[8] = {0.f, 0.f, 0.f, 0.f, 0.f, 0.f, 0.f, 0.f};
    for (int v = 0; v < kV; ++v) {
      float coef = ha[v * kV + w];
      union { uint4 u; __bf16 h[8]; } ld;
      ld.u = *reinterpret_cast<const uint4*>(tile + v * kDim + c8 * 8);
#pragma unroll
      for (int j = 0; j < 8; ++j) acc[j] += coef * (float)ld.h[j];
    }
    union { uint4 u; __bf16 h[8]; } pk;
    float s8 = 0.f, d8 = 0.f;
#pragma unroll
    for (int j = 0; j < 8; ++j) {
      pk.h[j] = (__bf16)acc[j];
      s8 += acc[j];
      d8 += w1[c8 * 8 + j] * acc[j];
    }
    *reinterpret_cast<uint4*>(OP + base + (size_t)w * kDim + c8 * 8) = pk.u;
    ssum += s8;
    dp[w * 24 + c8] = d8;
  }
  for (int off = 32; off > 0; off >>= 1) ssum += __shfl_down(ssum, off);
  if ((tid & 63) == 0) red[tid >> 6] = ssum;
  __syncthreads();
  if (tid == 0)
    s_out[nt] = (red[0] + red[1] + red[2] + red[3]) *
                (1.f / (float)(kDim * kV));
  // d-term reduce: dtbl[nt*150 + h*25 + w] = sum_{c8 in head h} dp[w][c8]
  if (tid < 150) {
    int w = tid / kH, h = tid - (tid / kH) * kH;
    float a = dp[w * 24 + h * 4] + dp[w * 24 + h * 4 + 1] +
              dp[w * 24 + h * 4 + 2] + dp[w * 24 + h * 4 + 3];
    dtbl[(size_t)nt * 150 + h * 25 + w] = a;
  }
}

// ---------------- SE gate MLP -> factor f[n,t] = 1 + 0.4*sigmoid(...) -------
__global__ void gate_kernel(const float* __restrict__ s,
                            const float* __restrict__ w1l,
                            const float* __restrict__ b1,
                            const float* __restrict__ w2l,
                            const float* __restrict__ b2,
                            float* __restrict__ gatef) {
  __shared__ float sh[kT];
  __shared__ float hid[12];
  int n = blockIdx.x, t = threadIdx.x;
  sh[t] = s[n * kT + t];
  __syncthreads();
  if (t < 12) {
    float a = b1[t];
    for (int j = 0; j < kT; ++j) a += sh[j] * w1l[t * kT + j];
    hid[t] = fmaxf(a, 0.f);
  }
  __syncthreads();
  float a = b2[t];
  for (int j = 0; j < 12; ++j) a += hid[j] * w2l[t * 12 + j];
  float g = 1.f / (1.f + __expf(-a));
  gatef[n * kT + t] = 1.f + kCoeff * g;
}

// ---------- MFMA attention: block = (n,t), 6 waves, wave = head ------------
// R16 structure, minus ef/kef/d-term (K pre-folded in gemm2; d-term from
// dtbl). P/OL stride 36, QR stride 17, hopsB staged. 28.4 KB LDS.
__global__ void __launch_bounds__(384) attn_kernel(
    const bf16* __restrict__ QK, const bf16* __restrict__ VT,
    const float* __restrict__ dtbl, const float* __restrict__ gatef,
    const int* __restrict__ hops, const bf16* __restrict__ RPEb,
    const float* __restrict__ outer, const float* __restrict__ alpha_p,
    const bf16* __restrict__ pwb, const float* __restrict__ proj_b,
    const float* __restrict__ x, float* __restrict__ out) {
  __shared__ ushort wls[kH][2304];
  __shared__ unsigned char hopsB[kV][32];
  const int tid = threadIdx.x;
  const int lane = tid & 63;
  const int h = tid >> 6;  // wave id = head
  const int t = blockIdx.x, n = blockIdx.y;
  const int nt = n * kT + t;
  const int lm = lane & 15, g = lane >> 4;
  const bool w1ok = (lm + 16) < kV;

  for (int i = tid; i < kV * 32; i += 384) {
    int v = i >> 5, w = i & 31;
    hopsB[v][w] = (w < kV) ? (unsigned char)hops[v * kV + w] : 0;
  }
  __syncthreads();

  bf16* Pp = (bf16*)&wls[h][0];       // [32][36]
  bf16* OLp = (bf16*)&wls[h][1152];   // [32][36]
  float* QRp = (float*)&wls[h][1152]; // [32][17] (alias, used before OLp)

  const float f = gatef[nt];
  const float alpha = alpha_p[0];
  const bf16* Qbase = QK + (size_t)(nt * kV) * 384;
  const int colO = h * kHd + g * 8;

  // ---- fragment loads (direct from global, k-contiguous 16B) ----
  bf16x8 qf[2], kf[2];
#pragma unroll
  for (int mf = 0; mf < 2; ++mf) {
    const bf16* row = Qbase + (size_t)(mf * 16 + lm) * 384;
    qf[mf] = *reinterpret_cast<const bf16x8*>(row + colO);
    kf[mf] = *reinterpret_cast<const bf16x8*>(row + kDim + colO);  // = K+f*E
  }
  bf16x8 rf = *reinterpret_cast<const bf16x8*>(RPEb + (h * 16 + lm) * kHd + g * 8);
  // d-term from precomputed table (raw; scaled by f below)
  const float* drow = dtbl + (size_t)nt * 150 + h * 25;
  float dt0 = f * drow[lm];
  float dt1 = w1ok ? f * drow[lm + 16] : 0.f;

  // ---- S = Q(KE)^T and QR = Q rpe^T via MFMA ----
  f32x4 aK[2][2] = {};
  f32x4 aR[2] = {};
#pragma unroll
  for (int mf = 0; mf < 2; ++mf) {
#pragma unroll
    for (int nf = 0; nf < 2; ++nf)
      aK[mf][nf] =
          __builtin_amdgcn_mfma_f32_16x16x32_bf16(qf[mf], kf[nf], aK[mf][nf], 0, 0, 0);
    aR[mf] = __builtin_amdgcn_mfma_f32_16x16x32_bf16(qf[mf], rf, aR[mf], 0, 0, 0);
  }

  // dump QR to LDS: QR[v][hp], stride 17 f32 (odd -> 16 distinct banks)
#pragma unroll
  for (int mf = 0; mf < 2; ++mf)
#pragma unroll
    for (int r = 0; r < 4; ++r)
      QRp[(mf * 16 + g * 4 + r) * 17 + lm] = aR[mf][r];

  // ---- epilogue: bias-gather + softmax (register butterfly) + P write ----
#pragma unroll
  for (int mf = 0; mf < 2; ++mf) {
#pragma unroll
    for (int r = 0; r < 4; ++r) {
      int v = mf * 16 + g * 4 + r;
      int vc = v < kV ? v : kV - 1;
      int hp0 = hopsB[vc][lm];
      int hp1 = hopsB[vc][lm + 16];
      float s0 = (aK[mf][0][r] + QRp[v * 17 + hp0] + dt0) * kScale;
      float s1 = (aK[mf][1][r] + QRp[v * 17 + hp1] + dt1) * kScale;
      if (!w1ok) s1 = -3.0e38f;
      float m = fmaxf(s0, s1);
#pragma unroll
      for (int d = 1; d < 16; d <<= 1) m = fmaxf(m, __shfl_xor(m, d));
      float e0 = __expf(s0 - m);
      float e1 = w1ok ? __expf(s1 - m) : 0.f;
      float sum = e0 + e1;
#pragma unroll
      for (int d = 1; d < 16; d <<= 1) sum += __shfl_xor(sum, d);
      float inv = alpha / sum;
      float o0 = outer[h * (kV * kV) + vc * kV + lm];
      float o1 = w1ok ? outer[h * (kV * kV) + vc * kV + lm + 16] : 0.f;
      Pp[v * 36 + lm] = __float2bfloat16(e0 * inv + o0);
      Pp[v * 36 + lm + 16] = __float2bfloat16(w1ok ? e1 * inv + o1 : 0.f);
    }
  }

  // ---- PV: O[v][d] = P @ V, V fragments straight from global VT ----
  bf16x8 pa[2], vb[2];
#pragma unroll
  for (int mf = 0; mf < 2; ++mf)
    pa[mf] = *reinterpret_cast<const bf16x8*>(Pp + (mf * 16 + lm) * 36 + g * 8);
#pragma unroll
  for (int nf = 0; nf < 2; ++nf)
    vb[nf] = *reinterpret_cast<const bf16x8*>(
        VT + ((size_t)(nt * kDim + h * kHd + nf * 16 + lm)) * 32 + g * 8);
  f32x4 aO[2][2] = {};
#pragma unroll
  for (int mf = 0; mf < 2; ++mf)
#pragma unroll
    for (int nf = 0; nf < 2; ++nf)
      aO[mf][nf] =
          __builtin_amdgcn_mfma_f32_16x16x32_bf16(pa[mf], vb[nf], aO[mf][nf], 0, 0, 0);

  // ---- O -> LDS (bf16), then grouped proj via MFMA (swapped operands:
  //      oo on regs, v on lanes -> coalesced residual load/store) ----
#pragma unroll
  for (int mf = 0; mf < 2; ++mf)
#pragma unroll
    for (int nf = 0; nf < 2; ++nf)
#pragma unroll
      for (int r = 0; r < 4; ++r)
        OLp[(mf * 16 + g * 4 + r) * 36 + nf * 16 + lm] =
            __float2bfloat16(aO[mf][nf][r]);

  bf16x8 oa[2], pwf[2];
#pragma unroll
  for (int nf = 0; nf < 2; ++nf)
    oa[nf] = *reinterpret_cast<const bf16x8*>(OLp + (nf * 16 + lm) * 36 + g * 8);
#pragma unroll
  for (int mf = 0; mf < 2; ++mf)
    pwf[mf] = *reinterpret_cast<const bf16x8*>(pwb +
        (h * kHd + mf * 16 + lm) * kHd + g * 8);
  f32x4 aF[2][2] = {};
#pragma unroll
  for (int mf = 0; mf < 2; ++mf)
#pragma unroll
    for (int nf = 0; nf < 2; ++nf)
      aF[mf][nf] =
          __builtin_amdgcn_mfma_f32_16x16x32_bf16(pwf[mf], oa[nf], aF[mf][nf], 0, 0, 0);

  // ---- bias + residual store into [n][c][t][v]: v on lanes = coalesced ----
#pragma unroll
  for (int mf = 0; mf < 2; ++mf) {
#pragma unroll
    for (int r = 0; r < 4; ++r) {
      int oo = mf * 16 + g * 4 + r;
      int c = h * kHd + oo;
      float pbv = proj_b[c];
      size_t gbase = (size_t)n * kNCstride + (size_t)c * kP + t * kV;
#pragma unroll
      for (int nf = 0; nf < 2; ++nf) {
        int v = nf * 16 + lm;
        if (v < kV) out[gbase + v] = x[gbase + v] + aF[mf][nf][r] + pbv;
      }
    }
  }
}

extern "C" void kernel_launch(void* const* d_in, const int* in_sizes, int n_in,
                              void* d_out, int out_size, void* d_ws,
                              size_t ws_size, hipStream_t stream) {
  const float* x = (const float*)d_in[0];
  const int* joint_label = (const int*)d_in[1];
  const float* he_weight = (const float*)d_in[3];
  const int* hops = (const int*)d_in[4];
  const float* ln_g = (const float*)d_in[5];
  const float* ln_b = (const float*)d_in[6];
  const float* hgc_w = (const float*)d_in[7];
  const float* q_w = (const float*)d_in[8];
  const float* kv_w = (const float*)d_in[9];
  const float* proj_w = (const float*)d_in[10];
  const float* proj_b = (const float*)d_in[11];
  const float* rpe = (const float*)d_in[12];
  const float* w1 = (const float*)d_in[13];
  const float* outer = (const float*)d_in[14];
  const float* alpha = (const float*)d_in[15];
  const float* lin1_w = (const float*)d_in[16];
  const float* lin1_b = (const float*)d_in[17];
  const float* lin2_w = (const float*)d_in[18];
  const float* lin2_b = (const float*)d_in[19];
  const int n_hop = in_sizes[12] / kDim;

  char* w = (char*)d_ws;
  bf16* QK = (bf16*)w;                        // [n][p][384], 78.6 MB
  w += (size_t)kN * kP * 2 * kDim * 2;
  bf16* XR = (bf16*)w;                        // [n][p][192] bf16(x), 39.3 MB
  w += (size_t)kN * kP * kDim * 2;
  bf16* OP = (bf16*)w;                        // [n][p][192]
  w += (size_t)kN * kP * kDim * 2;
  w += 65536;                                 // slack for padded-row overreads
  bf16* VT = (bf16*)w;                        // [n*t][192][32], 50.3 MB
  w += (size_t)kN * kT * kDim * 32 * 2;
  bf16* Wb = (bf16*)w;                        // 768x192 bf16
  w += (size_t)768 * kDim * 2;
  bf16* RPEb = (bf16*)w;                      // [6][16][32] bf16
  w += (size_t)kH * 16 * kHd * 2;
  bf16* pwb = (bf16*)w;                       // [192][32] bf16
  w += (size_t)kDim * kHd * 2;
  float* hadj = (float*)w;
  w += 1024 * 4;
  float* s_ws = (float*)w;
  w += kN * kT * 4;
  float* gatef = (float*)w;
  w += kN * kT * 4;
  float* mu = (float*)w;
  w += (size_t)kN * kP * 4;
  float* rstd = (float*)w;
  w += (size_t)kN * kP * 4;
  float* G = (float*)w;
  w += 576 * 4;
  float* Bb = (float*)w;
  w += 576 * 4;
  float* dtbl = (float*)w;                    // [nt][6][25] d-term table
  w += (size_t)kN * kT * 150 * 4;

  hipLaunchKernelGGL(setup_kernel, dim3(3794), dim3(256), 0, stream,
                     joint_label, he_weight, hgc_w, q_w, kv_w, rpe, proj_w,
                     ln_g, ln_b, n_hop, hadj, Wb, G, Bb, RPEb, pwb, VT);
  hipLaunchKernelGGL(prep_kernel, dim3(kT, kN), dim3(256), 0, stream, x, XR,
                     mu, rstd);
  // OP = hgc_w @ x (raw); h_adj applied afterwards (commutes)
  hipLaunchKernelGGL((mfma_gemm_kernel<3, kDim, false, false>),
                     dim3(25 * 3 * kN), dim3(64), 0, stream, Wb, XR, OP,
                     (bf16*)nullptr, nullptr, nullptr, nullptr, nullptr,
                     (const bf16*)nullptr, nullptr);
  hipLaunchKernelGGL(haapply_kernel, dim3(kT, kN), dim3(256), 0, stream, OP,
                     hadj, w1, s_ws, dtbl);
  hipLaunchKernelGGL(gate_kernel, dim3(kN), dim3(kT), 0, stream, s_ws, lin1_w,
                     lin1_b, lin2_w, lin2_b, gatef);
  // QK/V = (Wg @ x) with LN folded; K part pre-folds += f*E (gate ready)
  hipLaunchKernelGGL((mfma_gemm_kernel<9, 384, true, true>),
                     dim3(25 * 9 * kN), dim3(64), 0, stream, Wb + 192 * kDim,
                     XR, QK, VT, mu, rstd, G, Bb, OP, gatef);
  hipLaunchKernelGGL(attn_kernel, dim3(kT, kN), dim3(384), 0, stream, QK, VT,
                     dtbl, gatef, hops, RPEb, outer, alpha, pwb, proj_b, x,
                     (float*)d_out);
}

// Round 20
// 332.039 us; speedup vs baseline: 1.0183x; 1.0183x over previous
//
#include <hip/hip_runtime.h>
#include <hip/hip_bf16.h>

using bf16 = __hip_bfloat16;
typedef __bf16 bf16x8 __attribute__((ext_vector_type(8)));
typedef float f32x4 __attribute__((ext_vector_type(4)));

constexpr int kDim = 192;
constexpr int kH = 6;
constexpr int kHd = 32;
constexpr int kN = 64;
constexpr int kT = 64;
constexpr int kV = 25;
constexpr int kP = kT * kV;            // 1600 positions per n
constexpr int kNCstride = kDim * kP;   // 307200, per-n stride of (c,t,v)
constexpr float kScale = 0.17677669529663687f;  // 32^-0.5
constexpr float kCoeff = 0.4f;

// ---- setup: h_adj, weights->bf16 (g folded), G/Bb, rpe/proj pack, VT pad ---
__global__ void __launch_bounds__(256) setup_kernel(
    const int* __restrict__ jl, const float* __restrict__ hew,
    const float* __restrict__ hgc, const float* __restrict__ qw,
    const float* __restrict__ kvw, const float* __restrict__ rpe,
    const float* __restrict__ proj_w, const float* __restrict__ lng,
    const float* __restrict__ lnb, int n_hop, float* __restrict__ hadj,
    bf16* __restrict__ Wb, float* __restrict__ G, float* __restrict__ Bb,
    bf16* __restrict__ RPEb, bf16* __restrict__ pwb, bf16* __restrict__ VT) {
  const int bid = blockIdx.x;
  const int tid = threadIdx.x;
  if (bid < 576) {  // Wb[768][192]: rows 0..191 hgc raw; 192..767 [q;kv]*g
    int i = bid * 256 + tid;
    float v;
    if (i < 36864) {
      v = hgc[i];
    } else {
      int local = i - 36864;
      int c = local % kDim;
      v = (local < 36864) ? qw[local] : kvw[local - 36864];
      v *= lng[c];
    }
    Wb[i] = __float2bfloat16(v);
  } else if (bid == 576) {  // h_adj from labels
    __shared__ int lbl[kV];
    __shared__ int cnt[8];
    if (tid < 8) cnt[tid] = 0;
    __syncthreads();
    if (tid < kV) { lbl[tid] = jl[tid]; atomicAdd(&cnt[lbl[tid]], 1); }
    __syncthreads();
    for (int idx = tid; idx < kV * kV; idx += 256) {
      int v = idx / kV, w = idx - v * kV;
      float val = 0.f;
      if (lbl[v] == lbl[w]) val = hew[lbl[v]] / (float)cnt[lbl[v]];
      hadj[idx] = val;
    }
  } else if (bid == 577) {  // pack rpe (zero-padded to 16 hops) + proj_w
    for (int i = tid; i < kH * 16 * kHd; i += 256) {
      int h = i >> 9, hp = (i >> 5) & 15, d = i & 31;
      float v = (hp < n_hop) ? rpe[hp * kDim + h * kHd + d] : 0.f;
      RPEb[i] = __float2bfloat16(v);
    }
    for (int i = tid; i < kDim * kHd; i += 256)
      pwb[i] = __float2bfloat16(proj_w[i]);
  } else if (bid < 722) {  // G[o] = sum W[o][c]*g[c]; Bb[o] = sum W[o][c]*b[c]
    int o = (bid - 578) * 4 + (tid >> 6);
    int lane = tid & 63;
    const float* Wr =
        (o < kDim) ? (qw + (size_t)o * kDim) : (kvw + (size_t)(o - kDim) * kDim);
    float gs = 0.f, bs = 0.f;
    for (int c = lane; c < kDim; c += 64) {
      float wv = Wr[c];
      gs += wv * lng[c];
      bs += wv * lnb[c];
    }
    for (int off = 32; off > 0; off >>= 1) {
      gs += __shfl_down(gs, off);
      bs += __shfl_down(bs, off);
    }
    if (lane == 0) { G[o] = gs; Bb[o] = bs; }
  } else {  // zero VT pad cols 24..31 (one 16B store per row)
    int row = (bid - 722) * 256 + tid;
    if (row < kN * kT * kDim) {
      uint4 z = {0u, 0u, 0u, 0u};
      *reinterpret_cast<uint4*>(reinterpret_cast<char*>(VT) + (size_t)row * 64 +
                                48) = z;
    }
  }
}

// ------- prep per (n,t): pure transpose f32->bf16 + LN stats, no data LDS ---
__global__ void __launch_bounds__(256) prep_kernel(
    const float* __restrict__ x, bf16* __restrict__ XR, float* __restrict__ mu,
    float* __restrict__ rstd) {
  __shared__ float ps[kV][25], ps2[kV][25];
  const int tid = threadIdx.x;
  const int t = blockIdx.x, n = blockIdx.y;
  const float* xb = x + (size_t)n * kNCstride + t * kV;
  size_t ob = ((size_t)n * kP + t * kV) * kDim;
  for (int idx = tid; idx < 600; idx += 256) {
    int p = idx % 25, c8 = idx / 25;  // p fastest -> coalesced row reads
    float a = 0.f, b = 0.f;
    union { uint4 u; __bf16 h[8]; } pk;
#pragma unroll
    for (int i = 0; i < 8; ++i) {
      float v = xb[(size_t)(c8 * 8 + i) * kP + p];
      a += v;
      b += v * v;
      pk.h[i] = (__bf16)v;
    }
    *reinterpret_cast<uint4*>(XR + ob + (size_t)p * kDim + c8 * 8) = pk.u;
    ps[p][c8] = a;
    ps2[p][c8] = b;
  }
  __syncthreads();
  if (tid < kV) {
    float a = 0.f, b = 0.f;
#pragma unroll
    for (int c8 = 0; c8 < 24; ++c8) { a += ps[tid][c8]; b += ps2[tid][c8]; }
    float m = a * (1.f / kDim);
    float var = b * (1.f / kDim) - m * m;
    int gid = n * kP + t * kV + tid;
    mu[gid] = m;
    rstd[gid] = rsqrtf(var + 1e-5f);
  }
}

// ---- MFMA GEMM: out[n][p][o] = A[o][k]*B[n][p][k]; optional LN-fix epilogue,
//      optional V-third -> VT transposed, optional K += f*E fold done in the
//      COALESCED store loop (E rows contiguous there). 1 wave/block. ----
template <int OBN, int MOUT, bool VS, bool LNF>
__global__ void __launch_bounds__(64) mfma_gemm_kernel(
    const bf16* __restrict__ A, const bf16* __restrict__ B,
    bf16* __restrict__ out, bf16* __restrict__ VT,
    const float* __restrict__ muA, const float* __restrict__ rsA,
    const float* __restrict__ G, const float* __restrict__ Bb,
    const bf16* __restrict__ OPe, const float* __restrict__ gatef) {
  __shared__ bf16 st[64][70];  // 8.96 KB, [p_local][o_local], stride 70
  int id = blockIdx.x;
  int per = gridDim.x >> 3;  // grid % 8 == 0
  int wg = (id & 7) * per + (id >> 3);
  int n = wg / (25 * OBN);
  int rem = wg - n * (25 * OBN);
  const int pb = (rem / OBN) * 64;
  const int ob = (rem % OBN) * 64;
  const int l = threadIdx.x;
  B += (size_t)n * kNCstride;
  out += (size_t)n * kP * MOUT;
  f32x4 acc[4][4] = {};
  const int lm = l & 15;
  const int lk = (l >> 4) * 8;
  for (int kb = 0; kb < kDim; kb += 32) {
    bf16x8 af[4], bfv[4];
#pragma unroll
    for (int mf = 0; mf < 4; ++mf)
      af[mf] = *reinterpret_cast<const bf16x8*>(
          A + (size_t)(ob + mf * 16 + lm) * kDim + kb + lk);
#pragma unroll
    for (int nf = 0; nf < 4; ++nf)
      bfv[nf] = *reinterpret_cast<const bf16x8*>(
          B + (size_t)(pb + nf * 16 + lm) * kDim + kb + lk);
#pragma unroll
    for (int mf = 0; mf < 4; ++mf)
#pragma unroll
      for (int nf = 0; nf < 4; ++nf)
        acc[mf][nf] = __builtin_amdgcn_mfma_f32_16x16x32_bf16(
            af[mf], bfv[nf], acc[mf][nf], 0, 0, 0);
  }
  const int r0 = (l >> 4) * 4;
  float rsv[4], muv[4];
  if (LNF) {
#pragma unroll
    for (int nf = 0; nf < 4; ++nf) {
      int p = pb + nf * 16 + lm;
      rsv[nf] = rsA[n * kP + p];
      muv[nf] = muA[n * kP + p];
    }
  }
  if (!VS || ob < 384) {
    // ---- QK/OP path: LN (opt) -> LDS [p][o] -> coalesced stores with
    //      optional K += f*E fold (E rows contiguous here) ----
#pragma unroll
    for (int mf = 0; mf < 4; ++mf) {
      const int o0 = ob + mf * 16 + r0;
      float ga[4] = {0.f, 0.f, 0.f, 0.f}, ba[4] = {0.f, 0.f, 0.f, 0.f};
      if (LNF) {
        float4 g4 = *reinterpret_cast<const float4*>(G + o0);
        float4 b4 = *reinterpret_cast<const float4*>(Bb + o0);
        ga[0] = g4.x; ga[1] = g4.y; ga[2] = g4.z; ga[3] = g4.w;
        ba[0] = b4.x; ba[1] = b4.y; ba[2] = b4.z; ba[3] = b4.w;
      }
#pragma unroll
      for (int nf = 0; nf < 4; ++nf) {
#pragma unroll
        for (int r = 0; r < 4; ++r) {
          float vvv = acc[mf][nf][r];
          if (LNF) vvv = rsv[nf] * (vvv - muv[nf] * ga[r]) + ba[r];
          st[nf * 16 + lm][mf * 16 + r0 + r] = __float2bfloat16(vvv);
        }
      }
    }
    __syncthreads();
    const bool kfold = VS && (ob >= 192);  // K range: fold += f*E on store
    const bf16* OPn = kfold ? (OPe + (size_t)n * kP * kDim) : nullptr;
#pragma unroll
    for (int it = 0; it < 8; ++it) {
      int pl = it * 8 + (l >> 3);
      int oc = (l & 7) * 8;
      if (kfold) {
        int p = pb + pl;
        float frow = gatef[n * kT + p / 25];
        union { uint4 u; __bf16 hh[8]; } sv, ev, pk;
        sv.u = *reinterpret_cast<const uint4*>(&st[pl][oc]);
        ev.u = *reinterpret_cast<const uint4*>(OPn + (size_t)p * kDim +
                                               (ob - 192) + oc);
#pragma unroll
        for (int j = 0; j < 8; ++j)
          pk.hh[j] = (__bf16)((float)sv.hh[j] + frow * (float)ev.hh[j]);
        *reinterpret_cast<uint4*>(out + (size_t)p * MOUT + ob + oc) = pk.u;
      } else {
        uint4 v = *reinterpret_cast<const uint4*>(&st[pl][oc]);
        *reinterpret_cast<uint4*>(out + (size_t)(pb + pl) * MOUT + ob + oc) = v;
      }
    }
  } else {  // V third: write transposed VT[(n*64+t)*192 + d][v]
    int tt[4], vv[4];
#pragma unroll
    for (int nf = 0; nf < 4; ++nf) {
      int p = pb + nf * 16 + lm;
      tt[nf] = p / 25;
      vv[nf] = p - tt[nf] * 25;
    }
#pragma unroll
    for (int mf = 0; mf < 4; ++mf) {
      const int o0 = ob + mf * 16 + r0;
      float ga[4], ba[4];
      float4 g4 = *reinterpret_cast<const float4*>(G + o0);
      float4 b4 = *reinterpret_cast<const float4*>(Bb + o0);
      ga[0] = g4.x; ga[1] = g4.y; ga[2] = g4.z; ga[3] = g4.w;
      ba[0] = b4.x; ba[1] = b4.y; ba[2] = b4.z; ba[3] = b4.w;
#pragma unroll
      for (int nf = 0; nf < 4; ++nf) {
        size_t rowb =
            ((size_t)(n * kT + tt[nf]) * kDim + (o0 - 384)) * 32 + vv[nf];
#pragma unroll
        for (int r = 0; r < 4; ++r) {
          float vvv = rsv[nf] * (acc[mf][nf][r] - muv[nf] * ga[r]) + ba[r];
          VT[rowb + (size_t)r * 32] = __float2bfloat16(vvv);
        }
      }
    }
  }
}

// ------ h_adj apply on OP (in place) + fused sred sum + d-term table -------
__global__ void __launch_bounds__(256) haapply_kernel(
    bf16* __restrict__ OP, const float* __restrict__ hadjg,
    const float* __restrict__ w1, float* __restrict__ s_out,
    float* __restrict__ dtbl) {
  __shared__ ushort tile[kV * kDim];  // 9.6 KB
  __shared__ float ha[640];
  __shared__ float red[4];
  __shared__ float dp[600];  // partials for d-term: [w][c8]
  const int tid = threadIdx.x;
  const int t = blockIdx.x, n = blockIdx.y;
  const int nt = n * kT + t;
  size_t base = ((size_t)nt * kV) * kDim;
  for (int i = tid; i < kV * kV; i += 256) ha[i] = hadjg[i];
  const uint2* src = reinterpret_cast<const uint2*>(OP + base);
  uint2* dst2 = reinterpret_cast<uint2*>(tile);
  for (int i = tid; i < kV * kDim / 4; i += 256) dst2[i] = src[i];
  __syncthreads();
  float ssum = 0.f;
  for (int idx = tid; idx < 600; idx += 256) {
    int c8 = idx % 24, w = idx / 24;  // c8 fastest -> coalesced writes
    float acc[8] = {0.f, 0.f, 0.f, 0.f, 0.f, 0.f, 0.f, 0.f};
    for (int v = 0; v < kV; ++v) {
      float coef = ha[v * kV + w];
      union { uint4 u; __bf16 h[8]; } ld;
      ld.u = *reinterpret_cast<const uint4*>(tile + v * kDim + c8 * 8);
#pragma unroll
      for (int j = 0; j < 8; ++j) acc[j] += coef * (float)ld.h[j];
    }
    union { uint4 u; __bf16 h[8]; } pk;
    float s8 = 0.f, d8 = 0.f;
#pragma unroll
    for (int j = 0; j < 8; ++j) {
      pk.h[j] = (__bf16)acc[j];
      s8 += acc[j];
      d8 += w1[c8 * 8 + j] * acc[j];
    }
    *reinterpret_cast<uint4*>(OP + base + (size_t)w * kDim + c8 * 8) = pk.u;
    ssum += s8;
    dp[w * 24 + c8] = d8;
  }
  for (int off = 32; off > 0; off >>= 1) ssum += __shfl_down(ssum, off);
  if ((tid & 63) == 0) red[tid >> 6] = ssum;
  __syncthreads();
  if (tid == 0)
    s_out[nt] = (red[0] + red[1] + red[2] + red[3]) *
                (1.f / (float)(kDim * kV));
  // d-term reduce: dtbl[nt*150 + h*25 + w] = sum_{c8 in head h} dp[w][c8]
  if (tid < 150) {
    int w = tid / kH, h = tid - (tid / kH) * kH;
    float a = dp[w * 24 + h * 4] + dp[w * 24 + h * 4 + 1] +
              dp[w * 24 + h * 4 + 2] + dp[w * 24 + h * 4 + 3];
    dtbl[(size_t)nt * 150 + h * 25 + w] = a;
  }
}

// ---------------- SE gate MLP -> factor f[n,t] = 1 + 0.4*sigmoid(...) -------
__global__ void gate_kernel(const float* __restrict__ s,
                            const float* __restrict__ w1l,
                            const float* __restrict__ b1,
                            const float* __restrict__ w2l,
                            const float* __restrict__ b2,
                            float* __restrict__ gatef) {
  __shared__ float sh[kT];
  __shared__ float hid[12];
  int n = blockIdx.x, t = threadIdx.x;
  sh[t] = s[n * kT + t];
  __syncthreads();
  if (t < 12) {
    float a = b1[t];
    for (int j = 0; j < kT; ++j) a += sh[j] * w1l[t * kT + j];
    hid[t] = fmaxf(a, 0.f);
  }
  __syncthreads();
  float a = b2[t];
  for (int j = 0; j < 12; ++j) a += hid[j] * w2l[t * 12 + j];
  float g = 1.f / (1.f + __expf(-a));
  gatef[n * kT + t] = 1.f + kCoeff * g;
}

// ---------- MFMA attention: block = (n,t), 6 waves, wave = head ------------
// R19 structure (attn measured 116 us): K pre-folded, d-term from dtbl.
__global__ void __launch_bounds__(384) attn_kernel(
    const bf16* __restrict__ QK, const bf16* __restrict__ VT,
    const float* __restrict__ dtbl, const float* __restrict__ gatef,
    const int* __restrict__ hops, const bf16* __restrict__ RPEb,
    const float* __restrict__ outer, const float* __restrict__ alpha_p,
    const bf16* __restrict__ pwb, const float* __restrict__ proj_b,
    const float* __restrict__ x, float* __restrict__ out) {
  __shared__ ushort wls[kH][2304];
  __shared__ unsigned char hopsB[kV][32];
  const int tid = threadIdx.x;
  const int lane = tid & 63;
  const int h = tid >> 6;  // wave id = head
  const int t = blockIdx.x, n = blockIdx.y;
  const int nt = n * kT + t;
  const int lm = lane & 15, g = lane >> 4;
  const bool w1ok = (lm + 16) < kV;

  for (int i = tid; i < kV * 32; i += 384) {
    int v = i >> 5, w = i & 31;
    hopsB[v][w] = (w < kV) ? (unsigned char)hops[v * kV + w] : 0;
  }
  __syncthreads();

  bf16* Pp = (bf16*)&wls[h][0];       // [32][36]
  bf16* OLp = (bf16*)&wls[h][1152];   // [32][36]
  float* QRp = (float*)&wls[h][1152]; // [32][17] (alias, used before OLp)

  const float f = gatef[nt];
  const float alpha = alpha_p[0];
  const bf16* Qbase = QK + (size_t)(nt * kV) * 384;
  const int colO = h * kHd + g * 8;

  // ---- fragment loads (direct from global, k-contiguous 16B) ----
  bf16x8 qf[2], kf[2];
#pragma unroll
  for (int mf = 0; mf < 2; ++mf) {
    const bf16* row = Qbase + (size_t)(mf * 16 + lm) * 384;
    qf[mf] = *reinterpret_cast<const bf16x8*>(row + colO);
    kf[mf] = *reinterpret_cast<const bf16x8*>(row + kDim + colO);  // = K+f*E
  }
  bf16x8 rf = *reinterpret_cast<const bf16x8*>(RPEb + (h * 16 + lm) * kHd + g * 8);
  // d-term from precomputed table (raw; scaled by f below)
  const float* drow = dtbl + (size_t)nt * 150 + h * 25;
  float dt0 = f * drow[lm];
  float dt1 = w1ok ? f * drow[lm + 16] : 0.f;

  // ---- S = Q(KE)^T and QR = Q rpe^T via MFMA ----
  f32x4 aK[2][2] = {};
  f32x4 aR[2] = {};
#pragma unroll
  for (int mf = 0; mf < 2; ++mf) {
#pragma unroll
    for (int nf = 0; nf < 2; ++nf)
      aK[mf][nf] =
          __builtin_amdgcn_mfma_f32_16x16x32_bf16(qf[mf], kf[nf], aK[mf][nf], 0, 0, 0);
    aR[mf] = __builtin_amdgcn_mfma_f32_16x16x32_bf16(qf[mf], rf, aR[mf], 0, 0, 0);
  }

  // dump QR to LDS: QR[v][hp], stride 17 f32 (odd -> 16 distinct banks)
#pragma unroll
  for (int mf = 0; mf < 2; ++mf)
#pragma unroll
    for (int r = 0; r < 4; ++r)
      QRp[(mf * 16 + g * 4 + r) * 17 + lm] = aR[mf][r];

  // ---- epilogue: bias-gather + softmax (register butterfly) + P write ----
#pragma unroll
  for (int mf = 0; mf < 2; ++mf) {
#pragma unroll
    for (int r = 0; r < 4; ++r) {
      int v = mf * 16 + g * 4 + r;
      int vc = v < kV ? v : kV - 1;
      int hp0 = hopsB[vc][lm];
      int hp1 = hopsB[vc][lm + 16];
      float s0 = (aK[mf][0][r] + QRp[v * 17 + hp0] + dt0) * kScale;
      float s1 = (aK[mf][1][r] + QRp[v * 17 + hp1] + dt1) * kScale;
      if (!w1ok) s1 = -3.0e38f;
      float m = fmaxf(s0, s1);
#pragma unroll
      for (int d = 1; d < 16; d <<= 1) m = fmaxf(m, __shfl_xor(m, d));
      float e0 = __expf(s0 - m);
      float e1 = w1ok ? __expf(s1 - m) : 0.f;
      float sum = e0 + e1;
#pragma unroll
      for (int d = 1; d < 16; d <<= 1) sum += __shfl_xor(sum, d);
      float inv = alpha / sum;
      float o0 = outer[h * (kV * kV) + vc * kV + lm];
      float o1 = w1ok ? outer[h * (kV * kV) + vc * kV + lm + 16] : 0.f;
      Pp[v * 36 + lm] = __float2bfloat16(e0 * inv + o0);
      Pp[v * 36 + lm + 16] = __float2bfloat16(w1ok ? e1 * inv + o1 : 0.f);
    }
  }

  // ---- PV: O[v][d] = P @ V, V fragments straight from global VT ----
  bf16x8 pa[2], vb[2];
#pragma unroll
  for (int mf = 0; mf < 2; ++mf)
    pa[mf] = *reinterpret_cast<const bf16x8*>(Pp + (mf * 16 + lm) * 36 + g * 8);
#pragma unroll
  for (int nf = 0; nf < 2; ++nf)
    vb[nf] = *reinterpret_cast<const bf16x8*>(
        VT + ((size_t)(nt * kDim + h * kHd + nf * 16 + lm)) * 32 + g * 8);
  f32x4 aO[2][2] = {};
#pragma unroll
  for (int mf = 0; mf < 2; ++mf)
#pragma unroll
    for (int nf = 0; nf < 2; ++nf)
      aO[mf][nf] =
          __builtin_amdgcn_mfma_f32_16x16x32_bf16(pa[mf], vb[nf], aO[mf][nf], 0, 0, 0);

  // ---- O -> LDS (bf16), then grouped proj via MFMA (swapped operands:
  //      oo on regs, v on lanes -> coalesced residual load/store) ----
#pragma unroll
  for (int mf = 0; mf < 2; ++mf)
#pragma unroll
    for (int nf = 0; nf < 2; ++nf)
#pragma unroll
      for (int r = 0; r < 4; ++r)
        OLp[(mf * 16 + g * 4 + r) * 36 + nf * 16 + lm] =
            __float2bfloat16(aO[mf][nf][r]);

  bf16x8 oa[2], pwf[2];
#pragma unroll
  for (int nf = 0; nf < 2; ++nf)
    oa[nf] = *reinterpret_cast<const bf16x8*>(OLp + (nf * 16 + lm) * 36 + g * 8);
#pragma unroll
  for (int mf = 0; mf < 2; ++mf)
    pwf[mf] = *reinterpret_cast<const bf16x8*>(pwb +
        (h * kHd + mf * 16 + lm) * kHd + g * 8);
  f32x4 aF[2][2] = {};
#pragma unroll
  for (int mf = 0; mf < 2; ++mf)
#pragma unroll
    for (int nf = 0; nf < 2; ++nf)
      aF[mf][nf] =
          __builtin_amdgcn_mfma_f32_16x16x32_bf16(pwf[mf], oa[nf], aF[mf][nf], 0, 0, 0);

  // ---- bias + residual store into [n][c][t][v]: v on lanes = coalesced ----
#pragma unroll
  for (int mf = 0; mf < 2; ++mf) {
#pragma unroll
    for (int r = 0; r < 4; ++r) {
      int oo = mf * 16 + g * 4 + r;
      int c = h * kHd + oo;
      float pbv = proj_b[c];
      size_t gbase = (size_t)n * kNCstride + (size_t)c * kP + t * kV;
#pragma unroll
      for (int nf = 0; nf < 2; ++nf) {
        int v = nf * 16 + lm;
        if (v < kV) out[gbase + v] = x[gbase + v] + aF[mf][nf][r] + pbv;
      }
    }
  }
}

extern "C" void kernel_launch(void* const* d_in, const int* in_sizes, int n_in,
                              void* d_out, int out_size, void* d_ws,
                              size_t ws_size, hipStream_t stream) {
  const float* x = (const float*)d_in[0];
  const int* joint_label = (const int*)d_in[1];
  const float* he_weight = (const float*)d_in[3];
  const int* hops = (const int*)d_in[4];
  const float* ln_g = (const float*)d_in[5];
  const float* ln_b = (const float*)d_in[6];
  const float* hgc_w = (const float*)d_in[7];
  const float* q_w = (const float*)d_in[8];
  const float* kv_w = (const float*)d_in[9];
  const float* proj_w = (const float*)d_in[10];
  const float* proj_b = (const float*)d_in[11];
  const float* rpe = (const float*)d_in[12];
  const float* w1 = (const float*)d_in[13];
  const float* outer = (const float*)d_in[14];
  const float* alpha = (const float*)d_in[15];
  const float* lin1_w = (const float*)d_in[16];
  const float* lin1_b = (const float*)d_in[17];
  const float* lin2_w = (const float*)d_in[18];
  const float* lin2_b = (const float*)d_in[19];
  const int n_hop = in_sizes[12] / kDim;

  char* w = (char*)d_ws;
  bf16* QK = (bf16*)w;                        // [n][p][384], 78.6 MB
  w += (size_t)kN * kP * 2 * kDim * 2;
  bf16* XR = (bf16*)w;                        // [n][p][192] bf16(x), 39.3 MB
  w += (size_t)kN * kP * kDim * 2;
  bf16* OP = (bf16*)w;                        // [n][p][192]
  w += (size_t)kN * kP * kDim * 2;
  w += 65536;                                 // slack for padded-row overreads
  bf16* VT = (bf16*)w;                        // [n*t][192][32], 50.3 MB
  w += (size_t)kN * kT * kDim * 32 * 2;
  bf16* Wb = (bf16*)w;                        // 768x192 bf16
  w += (size_t)768 * kDim * 2;
  bf16* RPEb = (bf16*)w;                      // [6][16][32] bf16
  w += (size_t)kH * 16 * kHd * 2;
  bf16* pwb = (bf16*)w;                       // [192][32] bf16
  w += (size_t)kDim * kHd * 2;
  float* hadj = (float*)w;
  w += 1024 * 4;
  float* s_ws = (float*)w;
  w += kN * kT * 4;
  float* gatef = (float*)w;
  w += kN * kT * 4;
  float* mu = (float*)w;
  w += (size_t)kN * kP * 4;
  float* rstd = (float*)w;
  w += (size_t)kN * kP * 4;
  float* G = (float*)w;
  w += 576 * 4;
  float* Bb = (float*)w;
  w += 576 * 4;
  float* dtbl = (float*)w;                    // [nt][6][25] d-term table
  w += (size_t)kN * kT * 150 * 4;

  hipLaunchKernelGGL(setup_kernel, dim3(3794), dim3(256), 0, stream,
                     joint_label, he_weight, hgc_w, q_w, kv_w, rpe, proj_w,
                     ln_g, ln_b, n_hop, hadj, Wb, G, Bb, RPEb, pwb, VT);
  hipLaunchKernelGGL(prep_kernel, dim3(kT, kN), dim3(256), 0, stream, x, XR,
                     mu, rstd);
  // OP = hgc_w @ x (raw); h_adj applied afterwards (commutes)
  hipLaunchKernelGGL((mfma_gemm_kernel<3, kDim, false, false>),
                     dim3(25 * 3 * kN), dim3(64), 0, stream, Wb, XR, OP,
                     (bf16*)nullptr, nullptr, nullptr, nullptr, nullptr,
                     (const bf16*)nullptr, nullptr);
  hipLaunchKernelGGL(haapply_kernel, dim3(kT, kN), dim3(256), 0, stream, OP,
                     hadj, w1, s_ws, dtbl);
  hipLaunchKernelGGL(gate_kernel, dim3(kN), dim3(kT), 0, stream, s_ws, lin1_w,
                     lin1_b, lin2_w, lin2_b, gatef);
  // QK/V = (Wg @ x) with LN folded; K part pre-folds += f*E in store loop
  hipLaunchKernelGGL((mfma_gemm_kernel<9, 384, true, true>),
                     dim3(25 * 9 * kN), dim3(64), 0, stream, Wb + 192 * kDim,
                     XR, QK, VT, mu, rstd, G, Bb, OP, gatef);
  hipLaunchKernelGGL(attn_kernel, dim3(kT, kN), dim3(384), 0, stream, QK, VT,
                     dtbl, gatef, hops, RPEb, outer, alpha, pwb, proj_b, x,
                     (float*)d_out);
}